// Round 14
// baseline (87.130 us; speedup 1.0000x reference)
//
#include <hip/hip_runtime.h>
#include <stdint.h>

// GAT: N=4096, F_in=512, H=8, F_out=64.
// P_ij = A_i·max(E1_j, R_i·E2_j)·adj, R_i = e^{-0.8 s_i}; A_i cancels in softmax.
// Round 14: barrier-free gat main loop — each jseg wave owns its LDS segments, so
// per-tile __syncthreads is replaced by per-wave counted s_waitcnt vmcnt(6)
// (T3/T4: loads for the next tile stay in flight; never drain to 0 mid-loop).
// setprio(1) around MFMA cluster (T5, free-running-wave regime). Quad-af + z=2
// + norm kernel retained from r13.

#define NN 4096
#define FIN 512
#define NH 8
#define FO 64

typedef _Float16 f16x8 __attribute__((ext_vector_type(8)));
typedef _Float16 f16x2 __attribute__((ext_vector_type(2)));
typedef __attribute__((ext_vector_type(4))) float f32x4;

union H8 { f16x8 v; f16x2 p[4]; unsigned u[4]; };
union U2 { unsigned u; f16x2 v; };

#define GLOAD_LDS16(g, l)                                                          \
  __builtin_amdgcn_global_load_lds((__attribute__((address_space(1))) const void*)(g), \
                                   (__attribute__((address_space(3))) void*)(l), 16, 0, 0)
#define GLOAD_LDS4(g, l)                                                           \
  __builtin_amdgcn_global_load_lds((__attribute__((address_space(1))) const void*)(g), \
                                   (__attribute__((address_space(3))) void*)(l), 4, 0, 0)
#define WAITVM(N) asm volatile("s_waitcnt vmcnt(" #N ")" ::: "memory")

__device__ __forceinline__ unsigned short f2h(float f) {
  _Float16 h = (_Float16)f;               // RNE
  return __builtin_bit_cast(unsigned short, h);
}

// ---------------- prep: adj->bitsT, X->fp16, W->WbT(fp16), wa = W^T a ----------------
__global__ __launch_bounds__(256) void prep_kernel(
    const float* __restrict__ X, const int* __restrict__ adj, const float* __restrict__ W,
    const float* __restrict__ a,
    unsigned short* __restrict__ Xh, unsigned short* __restrict__ WbT,
    unsigned* __restrict__ adjbitsT, unsigned short* __restrict__ WAh) {
  int bid = blockIdx.x, tid = threadIdx.x;
  if (bid < 2048) {                       // adj -> bit words, transposed [jt][r]
    int item = bid * 256 + tid;           // item = jt*4096 + r
    int jt = item >> 12, r = item & 4095;
    const int* p = adj + (size_t)r * NN + jt * 32;
    unsigned bits = 0;
#pragma unroll
    for (int b = 0; b < 32; b += 4) {
      int4 v = *(const int4*)(p + b);
      bits |= (unsigned)(v.x & 1) << b;
      bits |= (unsigned)(v.y & 1) << (b + 1);
      bits |= (unsigned)(v.z & 1) << (b + 2);
      bits |= (unsigned)(v.w & 1) << (b + 3);
    }
    adjbitsT[item] = bits;
  } else if (bid < 4096) {                // X -> fp16
    int item = (bid - 2048) * 256 + tid;
    float4 v = ((const float4*)X)[item];
    ushort4 o;
    o.x = f2h(v.x); o.y = f2h(v.y); o.z = f2h(v.z); o.w = f2h(v.w);
    ((ushort4*)Xh)[item] = o;
  } else if (bid < 5120) {                // W[h][k][o] -> WbT[h][o][k], coalesced READ
    int item = (bid - 4096) * 256 + tid;  // item = (h,k,o): wave reads 256B segment
    int o = item & 63, k = (item >> 6) & 511, h = item >> 15;
    WbT[h * 32768 + o * 512 + k] = f2h(W[h * 32768 + k * 64 + o]);
  } else {                                // wa[t][k] = sum_o W[h][k][o] * a[h][which*64+o]
    int item = (bid - 5120) * 256 + tid;  // 8192 items: t = h*2+which, k
    int h = item >> 10, which = (item >> 9) & 1, k = item & 511;
    const float4* wp = (const float4*)(W + ((size_t)h * FIN + k) * FO);
    const float4* ap = (const float4*)(a + h * 128 + which * 64);
    float s = 0.f;
#pragma unroll
    for (int o4 = 0; o4 < 16; ++o4) {
      float4 w4 = wp[o4], a4 = ap[o4];
      s += w4.x * a4.x + w4.y * a4.y + w4.z * a4.z + w4.w * a4.w;
    }
    WAh[(h * 2 + which) * FIN + k] = f2h(s);
  }
}

// ---------------- proj (+sd): 2-way K-split jobs; sd blocks at bx>=512 -------------
// D layout (16x16x32): col = lane&15, row = (lane>>4)*4 + reg   [m89]
__global__ __launch_bounds__(512, 4) void proj_sd_kernel(
    const unsigned short* __restrict__ Xh, const unsigned short* __restrict__ WbT,
    const unsigned short* __restrict__ WAh,
    unsigned short* __restrict__ Whfrag, float* __restrict__ Rf,
    unsigned short* __restrict__ E1h, unsigned short* __restrict__ E2h) {
  __shared__ float red[4 * 64 * 20];      // 20KB partial store
  int lane = threadIdx.x & 63, wave = threadIdx.x >> 6;
  int row16 = lane & 15, grp = lane >> 4;
  int bx = blockIdx.x;
  if (bx >= 512) {                        // sd: [s,d]x8 = X @ WA  (16 cols, K=512)
    int i0 = ((bx - 512) * 8 + wave) * 16;
    if (i0 >= NN) return;
    f32x4 acc = {0, 0, 0, 0};
    const unsigned short* xb = Xh + (size_t)(i0 + row16) * FIN + grp * 8;
    const unsigned short* wb = WAh + row16 * FIN + grp * 8;
#pragma unroll
    for (int k0 = 0; k0 < FIN; k0 += 32)
      acc = __builtin_amdgcn_mfma_f32_16x16x32_f16(*(const f16x8*)(xb + k0),
                                                   *(const f16x8*)(wb + k0), acc, 0, 0, 0);
    int hh = row16 >> 1;
#pragma unroll
    for (int reg = 0; reg < 4; ++reg) {
      int rr = i0 + grp * 4 + reg;
      float v = acc[reg];
      if (row16 & 1) {                    // d -> col tables fp16, PRE-HALVED
        E1h[hh * NN + rr] = f2h(0.5f * __expf(v));
        E2h[hh * NN + rr] = f2h(0.5f * __expf(0.2f * v));
      } else {                            // s -> row table R = e^{-0.8 s}
        Rf[hh * NN + rr] = __expf(-0.8f * v);
      }
    }
    return;
  }
  int kh = wave >> 2, jb = wave & 3;
  int job = bx * 4 + jb;                  // 2048 jobs = 256 rowtiles x 8 heads
  int h = job & 7, rt = job >> 3;
  int i0 = rt * 16;
  f32x4 acc[4] = {{0,0,0,0},{0,0,0,0},{0,0,0,0},{0,0,0,0}};
  const unsigned short* xb = Xh + (size_t)(i0 + row16) * FIN + kh * 256 + grp * 8;
  const unsigned short* wb = WbT + h * (FO * FIN) + row16 * FIN + kh * 256 + grp * 8;
#pragma unroll
  for (int k0 = 0; k0 < 256; k0 += 32) {
    f16x8 af = *(const f16x8*)(xb + k0);
#pragma unroll
    for (int cb = 0; cb < 4; ++cb)
      acc[cb] = __builtin_amdgcn_mfma_f32_16x16x32_f16(
          af, *(const f16x8*)(wb + cb * 16 * FIN + k0), acc[cb], 0, 0, 0);
  }
  if (kh == 1) {
    float* q = red + (jb * 64 + lane) * 20;
#pragma unroll
    for (int cb = 0; cb < 4; ++cb) *(f32x4*)(q + cb * 4) = acc[cb];
  }
  __syncthreads();
  if (kh == 0) {
    const float* q = red + (jb * 64 + lane) * 20;
#pragma unroll
    for (int cb = 0; cb < 4; ++cb) acc[cb] += *(const f32x4*)(q + cb * 4);
    // Whfrag[h][jt][cb][l][e] = Wh[jt*32 + (l>>4)*8 + e][cb*16 + (l&15)]
    int jt = i0 >> 5;
    int kk0 = (i0 & 31) + grp * 4;
    int tl = (kk0 >> 3) * 16 + row16;
    int e0 = kk0 & 7;
#pragma unroll
    for (int cb = 0; cb < 4; ++cb) {
      ushort4 pk;
      pk.x = f2h(acc[cb][0]); pk.y = f2h(acc[cb][1]);
      pk.z = f2h(acc[cb][2]); pk.w = f2h(acc[cb][3]);
      *(ushort4*)(Whfrag + (((size_t)h * 128 + jt) * 4 + cb) * 512 + tl * 8 + e0) = pk;
    }
  }
}

// ---------------- gat: quad-af, wave-private segs, barrier-free counted vmcnt -----
// SEG per tile: [B 4096 | E 128 | adj 256] = 4480 -> 4608; x dbuf x 4 jseg = 36864.
#define SEGB 4608
#define E_OFF 4096
#define A_OFF 4224

__global__ __launch_bounds__(256, 3) void gat_kernel(
    const unsigned* __restrict__ adjbitsT, const unsigned short* __restrict__ Whfrag,
    const float* __restrict__ Rf, const unsigned short* __restrict__ E1h,
    const unsigned short* __restrict__ E2h,
    float* __restrict__ N0, float* __restrict__ outbuf, float* __restrict__ Dd) {
  __shared__ __align__(16) char lds[36864];
  int h = blockIdx.y, z = blockIdx.z;
  int lane = threadIdx.x & 63, jseg = threadIdx.x >> 6;
  int row16 = lane & 15, grp = lane >> 4;
  int r0 = blockIdx.x * 64;
  int jt0 = z * 64 + jseg * 16;

  f16x2 Rh[4];
#pragma unroll
  for (int gi = 0; gi < 4; ++gi) {
    _Float16 rv = (_Float16)Rf[h * NN + r0 + gi * 16 + row16];
    Rh[gi][0] = rv; Rh[gi][1] = rv;
  }

  H8 ones;
#pragma unroll
  for (int k = 0; k < 4; ++k) ones.u[k] = 0x3C003C00u;   // fp16 1.0 pairs

  const unsigned short* wsrc = Whfrag + (size_t)h * 262144 + (size_t)jt0 * 2048 + lane * 8;
  const unsigned short* esrc =
      ((lane & 4) ? E2h : E1h) + h * NN + jt0 * 32 + (lane & 3) * 8;
  const unsigned* asrc = adjbitsT + (size_t)jt0 * NN + r0 + lane;

  f32x4 acc[4][5];
#pragma unroll
  for (int gi = 0; gi < 4; ++gi)
#pragma unroll
    for (int cc = 0; cc < 5; ++cc) acc[gi][cc] = (f32x4){0, 0, 0, 0};

  char* seg0 = lds + (jseg * 2 + 0) * SEGB;
  char* seg1 = lds + (jseg * 2 + 1) * SEGB;

  auto stage = [&](char* seg, int p) {     // 6 loads/tile/wave (uniform: lane<8 always
    const unsigned short* bs = wsrc + (size_t)p * 2048;  //  has active lanes)
    GLOAD_LDS16(bs, seg);
    GLOAD_LDS16(bs + 512, seg + 1024);
    GLOAD_LDS16(bs + 1024, seg + 2048);
    GLOAD_LDS16(bs + 1536, seg + 3072);
    GLOAD_LDS4(asrc + (size_t)p * NN, seg + A_OFF);          // 64 rows of adj bits
    if (lane < 8) GLOAD_LDS16(esrc + p * 32, seg + E_OFF);   // e1 | e2 (pre-halved)
  };

  auto compute = [&](const char* seg) {
    H8 e1, e2;
    e1.v = *(const f16x8*)(seg + E_OFF + grp * 16);
    e2.v = *(const f16x8*)(seg + E_OFF + 64 + grp * 16);
    const char* bp = seg + lane * 16;
    f16x8 b0 = *(const f16x8*)(bp);
    f16x8 b1 = *(const f16x8*)(bp + 1024);
    f16x8 b2 = *(const f16x8*)(bp + 2048);
    f16x8 b3 = *(const f16x8*)(bp + 3072);
    __builtin_amdgcn_s_setprio(1);
#pragma unroll
    for (int gi = 0; gi < 4; ++gi) {
      unsigned bw = *(const unsigned*)(seg + A_OFF + (gi * 16 + row16) * 4);
      unsigned bb = (bw >> (grp * 8)) & 0xffu;
      unsigned t = bb | (bb << 15);        // bit k at {k, k+15}
      H8 af;
#pragma unroll
      for (int k = 0; k < 4; ++k) {
        f16x2 mx = __builtin_elementwise_max(e1.p[k], Rh[gi] * e2.p[k]);
        U2 m;                              // bit2k->pos14, bit2k+1->pos30 (fp16 2.0)
        m.u = (t << (14 - 2 * k)) & 0x40004000u;
        af.p[k] = mx * m.v;
      }
      acc[gi][0] = __builtin_amdgcn_mfma_f32_16x16x32_f16(af.v, b0, acc[gi][0], 0, 0, 0);
      acc[gi][1] = __builtin_amdgcn_mfma_f32_16x16x32_f16(af.v, b1, acc[gi][1], 0, 0, 0);
      acc[gi][2] = __builtin_amdgcn_mfma_f32_16x16x32_f16(af.v, b2, acc[gi][2], 0, 0, 0);
      acc[gi][3] = __builtin_amdgcn_mfma_f32_16x16x32_f16(af.v, b3, acc[gi][3], 0, 0, 0);
      acc[gi][4] = __builtin_amdgcn_mfma_f32_16x16x32_f16(af.v, ones.v, acc[gi][4], 0, 0, 0);
    }
    __builtin_amdgcn_s_setprio(0);
  };

  // ---- barrier-free pipeline: tiles 0..15, one tile (6 loads) always in flight ----
  stage(seg0, 0);
  stage(seg1, 1);
#pragma unroll 1
  for (int p2 = 0; p2 < 7; ++p2) {
    WAITVM(6);                 // tile 2*p2 landed (next tile's 6 loads in flight)
    compute(seg0);             // ds_reads lgkm-drained before MFMAs -> safe to restage
    stage(seg0, 2 * p2 + 2);
    WAITVM(6);
    compute(seg1);
    stage(seg1, 2 * p2 + 3);
  }
  WAITVM(6);
  compute(seg0);               // tile 14
  WAITVM(0);
  compute(seg1);               // tile 15

  // ---- chunked cross-jseg reduction (overlay; barrier now required) ----
  __syncthreads();
  float* red = (float*)lds;               // 3 segs x 4 gi x 64 lanes x 16B = 12288 B
#pragma unroll
  for (int cc = 0; cc < 5; ++cc) {
    if (jseg != 0) {
#pragma unroll
      for (int gi = 0; gi < 4; ++gi)
        *(f32x4*)(red + (((jseg - 1) * 4 + gi) * 64 + lane) * 4) = acc[gi][cc];
    }
    __syncthreads();
    if (jseg == 0) {
#pragma unroll
      for (int s = 0; s < 3; ++s)
#pragma unroll
        for (int gi = 0; gi < 4; ++gi)
          acc[gi][cc] += *(const f32x4*)(red + ((s * 4 + gi) * 64 + lane) * 4);
    }
    __syncthreads();
  }

  if (jseg == 0) {
    float* base;
    int rs;
    if (z == 0) { base = N0 + (size_t)h * NN * FO; rs = FO; }
    else        { base = outbuf + h * FO;          rs = NH * FO; }
#pragma unroll
    for (int gi = 0; gi < 4; ++gi) {
#pragma unroll
      for (int reg = 0; reg < 4; ++reg) {
        int row = r0 + gi * 16 + grp * 4 + reg;
        float* op = base + (size_t)row * rs + row16;
        op[0]  = acc[gi][0][reg];
        op[16] = acc[gi][1][reg];
        op[32] = acc[gi][2][reg];
        op[48] = acc[gi][3][reg];
      }
      if (row16 == 0) {
#pragma unroll
        for (int reg = 0; reg < 4; ++reg)
          Dd[((size_t)z * NH + h) * NN + r0 + gi * 16 + grp * 4 + reg] = acc[gi][4][reg];
      }
    }
  }
}

// ---------------- reduce + normalize --------------------
__global__ __launch_bounds__(256) void norm_kernel(
    const float* __restrict__ N0, const float* __restrict__ Dd, float* __restrict__ out) {
  int idx = (blockIdx.x * 256 + threadIdx.x) * 4;      // over 4096*512 f32
  int r = idx >> 9, c = idx & 511, h = c >> 6, o = c & 63;
  float4 n1 = *(const float4*)(out + idx);
  float4 n0 = *(const float4*)(N0 + ((size_t)h * NN + r) * FO + o);
  float inv = 1.0f / (Dd[h * NN + r] + Dd[(NH + h) * NN + r]);
  float4 res;
  res.x = (n1.x + n0.x) * inv;
  res.y = (n1.y + n0.y) * inv;
  res.z = (n1.z + n0.z) * inv;
  res.w = (n1.w + n0.w) * inv;
  *(float4*)(out + idx) = res;
}

extern "C" void kernel_launch(void* const* d_in, const int* in_sizes, int n_in,
                              void* d_out, int out_size, void* d_ws, size_t ws_size,
                              hipStream_t stream) {
  const float* X  = (const float*)d_in[0];
  const int* adj  = (const int*)d_in[1];
  const float* W  = (const float*)d_in[2];
  const float* a  = (const float*)d_in[3];
  float* out = (float*)d_out;
  char* ws = (char*)d_ws;

  unsigned short* Xh     = (unsigned short*)(ws + 0);          // 4 MB
  unsigned short* WbT    = (unsigned short*)(ws + 4194304);    // 512 KB
  unsigned* adjbitsT     = (unsigned*)(ws + 4718592);          // 2 MB
  unsigned short* Whfrag = (unsigned short*)(ws + 6815744);    // 4 MB
  unsigned short* WAh    = (unsigned short*)(ws + 11010048);   // 16 KB
  float* Rf              = (float*)(ws + 11026432);            // 128 KB
  unsigned short* E1h    = (unsigned short*)(ws + 11288576);   // 64 KB
  unsigned short* E2h    = (unsigned short*)(ws + 11354112);   // 64 KB
  float* N0              = (float*)(ws + 11534336);            // 8 MB
  float* Dd              = (float*)(ws + 19922944);            // 256 KB (total ~20.2 MB)

  prep_kernel<<<5152, 256, 0, stream>>>(X, adj, W, a, Xh, WbT, adjbitsT, WAh);
  proj_sd_kernel<<<544, 512, 0, stream>>>(Xh, WbT, WAh, Whfrag, Rf, E1h, E2h);
  gat_kernel<<<dim3(64, 8, 2), 256, 0, stream>>>(adjbitsT, Whfrag, Rf, E1h, E2h, N0, out, Dd);
  norm_kernel<<<2048, 256, 0, stream>>>(N0, Dd, out);
}

// Round 15
// 84.956 us; speedup vs baseline: 1.0256x; 1.0256x over previous
//
#include <hip/hip_runtime.h>
#include <stdint.h>

// GAT: N=4096, F_in=512, H=8, F_out=64.
// P_ij = A_i·max(E1_j, R_i·E2_j)·adj, R_i = e^{-0.8 s_i}; A_i cancels in softmax.
// Round 15: 3-kernel structure (no z-split/norm). gat = quad-af full-sweep:
// 4 waves x (64 rows, 32 tiles), in-block 4-jseg chunked reduce (static indices),
// direct out write. prep drops the X pass (proj converts f32 X on the fly).

#define NN 4096
#define FIN 512
#define NH 8
#define FO 64

typedef _Float16 f16x8 __attribute__((ext_vector_type(8)));
typedef _Float16 f16x2 __attribute__((ext_vector_type(2)));
typedef __attribute__((ext_vector_type(4))) float f32x4;

union H8 { f16x8 v; f16x2 p[4]; unsigned u[4]; };
union U2 { unsigned u; f16x2 v; };

#define GLOAD_LDS16(g, l)                                                          \
  __builtin_amdgcn_global_load_lds((__attribute__((address_space(1))) const void*)(g), \
                                   (__attribute__((address_space(3))) void*)(l), 16, 0, 0)
#define GLOAD_LDS4(g, l)                                                           \
  __builtin_amdgcn_global_load_lds((__attribute__((address_space(1))) const void*)(g), \
                                   (__attribute__((address_space(3))) void*)(l), 4, 0, 0)

__device__ __forceinline__ unsigned short f2h(float f) {
  _Float16 h = (_Float16)f;               // RNE
  return __builtin_bit_cast(unsigned short, h);
}

__device__ __forceinline__ f16x8 ld_cvt8(const float* p) {   // f32x8 -> f16x8
  float4 a = *(const float4*)p, b = *(const float4*)(p + 4);
  f16x8 r;
  r[0] = (_Float16)a.x; r[1] = (_Float16)a.y; r[2] = (_Float16)a.z; r[3] = (_Float16)a.w;
  r[4] = (_Float16)b.x; r[5] = (_Float16)b.y; r[6] = (_Float16)b.z; r[7] = (_Float16)b.w;
  return r;
}

// ---------------- prep: adj->bitsT, W->WbT(fp16), wa = W^T a (no X pass) ----------
__global__ __launch_bounds__(256) void prep_kernel(
    const int* __restrict__ adj, const float* __restrict__ W, const float* __restrict__ a,
    unsigned short* __restrict__ WbT, unsigned* __restrict__ adjbitsT,
    unsigned short* __restrict__ WAh) {
  int bid = blockIdx.x, tid = threadIdx.x;
  if (bid < 2048) {                       // adj -> bit words, transposed [jt][r]
    int item = bid * 256 + tid;           // item = jt*4096 + r
    int jt = item >> 12, r = item & 4095;
    const int* p = adj + (size_t)r * NN + jt * 32;
    unsigned bits = 0;
#pragma unroll
    for (int b = 0; b < 32; b += 4) {
      int4 v = *(const int4*)(p + b);
      bits |= (unsigned)(v.x & 1) << b;
      bits |= (unsigned)(v.y & 1) << (b + 1);
      bits |= (unsigned)(v.z & 1) << (b + 2);
      bits |= (unsigned)(v.w & 1) << (b + 3);
    }
    adjbitsT[item] = bits;
  } else if (bid < 3072) {                // W[h][k][o] -> WbT[h][o][k], coalesced READ
    int item = (bid - 2048) * 256 + tid;  // 262144 items
    int o = item & 63, k = (item >> 6) & 511, h = item >> 15;
    WbT[h * 32768 + o * 512 + k] = f2h(W[h * 32768 + k * 64 + o]);
  } else {                                // wa[t][k] = sum_o W[h][k][o] * a[h][which*64+o]
    int item = (bid - 3072) * 256 + tid;  // 8192 items: t = h*2+which, k
    int h = item >> 10, which = (item >> 9) & 1, k = item & 511;
    const float4* wp = (const float4*)(W + ((size_t)h * FIN + k) * FO);
    const float4* ap = (const float4*)(a + h * 128 + which * 64);
    float s = 0.f;
#pragma unroll
    for (int o4 = 0; o4 < 16; ++o4) {
      float4 w4 = wp[o4], a4 = ap[o4];
      s += w4.x * a4.x + w4.y * a4.y + w4.z * a4.z + w4.w * a4.w;
    }
    WAh[(h * 2 + which) * FIN + k] = f2h(s);
  }
}

// ---------------- proj (+sd): reads f32 X directly; 2-way K-split jobs -------------
// D layout (16x16x32): col = lane&15, row = (lane>>4)*4 + reg   [m89]
__global__ __launch_bounds__(512, 4) void proj_sd_kernel(
    const float* __restrict__ X, const unsigned short* __restrict__ WbT,
    const unsigned short* __restrict__ WAh,
    unsigned short* __restrict__ Whfrag, float* __restrict__ Rf,
    unsigned short* __restrict__ E1h, unsigned short* __restrict__ E2h) {
  __shared__ float red[4 * 64 * 20];      // 20KB partial store
  int lane = threadIdx.x & 63, wave = threadIdx.x >> 6;
  int row16 = lane & 15, grp = lane >> 4;
  int bx = blockIdx.x;
  if (bx >= 512) {                        // sd: [s,d]x8 = X @ WA  (16 cols, K=512)
    int i0 = ((bx - 512) * 8 + wave) * 16;
    if (i0 >= NN) return;
    f32x4 acc = {0, 0, 0, 0};
    const float* xb = X + (size_t)(i0 + row16) * FIN + grp * 8;
    const unsigned short* wb = WAh + row16 * FIN + grp * 8;
#pragma unroll
    for (int k0 = 0; k0 < FIN; k0 += 32)
      acc = __builtin_amdgcn_mfma_f32_16x16x32_f16(ld_cvt8(xb + k0),
                                                   *(const f16x8*)(wb + k0), acc, 0, 0, 0);
    int hh = row16 >> 1;
#pragma unroll
    for (int reg = 0; reg < 4; ++reg) {
      int rr = i0 + grp * 4 + reg;
      float v = acc[reg];
      if (row16 & 1) {                    // d -> col tables fp16, PRE-HALVED
        E1h[hh * NN + rr] = f2h(0.5f * __expf(v));
        E2h[hh * NN + rr] = f2h(0.5f * __expf(0.2f * v));
      } else {                            // s -> row table R = e^{-0.8 s}
        Rf[hh * NN + rr] = __expf(-0.8f * v);
      }
    }
    return;
  }
  int kh = wave >> 2, jb = wave & 3;
  int job = bx * 4 + jb;                  // 2048 jobs = 256 rowtiles x 8 heads
  int h = job & 7, rt = job >> 3;
  int i0 = rt * 16;
  f32x4 acc[4] = {{0,0,0,0},{0,0,0,0},{0,0,0,0},{0,0,0,0}};
  const float* xb = X + (size_t)(i0 + row16) * FIN + kh * 256 + grp * 8;
  const unsigned short* wb = WbT + h * (FO * FIN) + row16 * FIN + kh * 256 + grp * 8;
#pragma unroll
  for (int k0 = 0; k0 < 256; k0 += 32) {
    f16x8 af = ld_cvt8(xb + k0);
#pragma unroll
    for (int cb = 0; cb < 4; ++cb)
      acc[cb] = __builtin_amdgcn_mfma_f32_16x16x32_f16(
          af, *(const f16x8*)(wb + cb * 16 * FIN + k0), acc[cb], 0, 0, 0);
  }
  if (kh == 1) {
    float* q = red + (jb * 64 + lane) * 20;
#pragma unroll
    for (int cb = 0; cb < 4; ++cb) *(f32x4*)(q + cb * 4) = acc[cb];
  }
  __syncthreads();
  if (kh == 0) {
    const float* q = red + (jb * 64 + lane) * 20;
#pragma unroll
    for (int cb = 0; cb < 4; ++cb) acc[cb] += *(const f32x4*)(q + cb * 4);
    // Whfrag[h][jt][cb][l][e] = Wh[jt*32 + (l>>4)*8 + e][cb*16 + (l&15)]
    int jt = i0 >> 5;
    int kk0 = (i0 & 31) + grp * 4;
    int tl = (kk0 >> 3) * 16 + row16;
    int e0 = kk0 & 7;
#pragma unroll
    for (int cb = 0; cb < 4; ++cb) {
      ushort4 pk;
      pk.x = f2h(acc[cb][0]); pk.y = f2h(acc[cb][1]);
      pk.z = f2h(acc[cb][2]); pk.w = f2h(acc[cb][3]);
      *(ushort4*)(Whfrag + (((size_t)h * 128 + jt) * 4 + cb) * 512 + tl * 8 + e0) = pk;
    }
  }
}

// ---------------- gat: quad-af full-sweep, 4 jseg waves x 32 tiles, in-block reduce
// SEG per tile: [B 4096 | E 128 | adj 256] = 4480 -> 4608; x dbuf x 4 jseg = 36864.
#define SEGB 4608
#define E_OFF 4096
#define A_OFF 4224

__global__ __launch_bounds__(256, 3) void gat_kernel(
    const unsigned* __restrict__ adjbitsT, const unsigned short* __restrict__ Whfrag,
    const float* __restrict__ Rf, const unsigned short* __restrict__ E1h,
    const unsigned short* __restrict__ E2h, float* __restrict__ out) {
  __shared__ __align__(16) char lds[36864];
  int h = blockIdx.y;
  int lane = threadIdx.x & 63, jseg = threadIdx.x >> 6;
  int row16 = lane & 15, grp = lane >> 4;
  int r0 = blockIdx.x * 64;
  int jt0 = jseg * 32;

  f16x2 Rh[4];
#pragma unroll
  for (int gi = 0; gi < 4; ++gi) {
    _Float16 rv = (_Float16)Rf[h * NN + r0 + gi * 16 + row16];
    Rh[gi][0] = rv; Rh[gi][1] = rv;
  }

  H8 ones;
#pragma unroll
  for (int k = 0; k < 4; ++k) ones.u[k] = 0x3C003C00u;   // fp16 1.0 pairs

  const unsigned short* wsrc = Whfrag + (size_t)h * 262144 + (size_t)jt0 * 2048 + lane * 8;
  const unsigned short* esrc =
      ((lane & 4) ? E2h : E1h) + h * NN + jt0 * 32 + (lane & 3) * 8;
  const unsigned* asrc = adjbitsT + (size_t)jt0 * NN + r0 + lane;

  f32x4 acc[4][5];
#pragma unroll
  for (int gi = 0; gi < 4; ++gi)
#pragma unroll
    for (int cc = 0; cc < 5; ++cc) acc[gi][cc] = (f32x4){0, 0, 0, 0};

  char* seg0 = lds + (jseg * 2 + 0) * SEGB;
  char* seg1 = lds + (jseg * 2 + 1) * SEGB;

  auto stage = [&](char* seg, int p) {     // stage tile jt0+p
    const unsigned short* bs = wsrc + (size_t)p * 2048;
    GLOAD_LDS16(bs, seg);
    GLOAD_LDS16(bs + 512, seg + 1024);
    GLOAD_LDS16(bs + 1024, seg + 2048);
    GLOAD_LDS16(bs + 1536, seg + 3072);
    GLOAD_LDS4(asrc + (size_t)p * NN, seg + A_OFF);          // 64 rows of adj bits
    if (lane < 8) GLOAD_LDS16(esrc + p * 32, seg + E_OFF);   // e1 | e2 (pre-halved)
  };

  auto compute = [&](const char* seg) {
    H8 e1, e2;
    e1.v = *(const f16x8*)(seg + E_OFF + grp * 16);
    e2.v = *(const f16x8*)(seg + E_OFF + 64 + grp * 16);
    const char* bp = seg + lane * 16;
    f16x8 b0 = *(const f16x8*)(bp);
    f16x8 b1 = *(const f16x8*)(bp + 1024);
    f16x8 b2 = *(const f16x8*)(bp + 2048);
    f16x8 b3 = *(const f16x8*)(bp + 3072);
#pragma unroll
    for (int gi = 0; gi < 4; ++gi) {
      unsigned bw = *(const unsigned*)(seg + A_OFF + (gi * 16 + row16) * 4);
      unsigned bb = (bw >> (grp * 8)) & 0xffu;
      unsigned t = bb | (bb << 15);        // bit k at {k, k+15}
      H8 af;
#pragma unroll
      for (int k = 0; k < 4; ++k) {
        f16x2 mx = __builtin_elementwise_max(e1.p[k], Rh[gi] * e2.p[k]);
        U2 m;                              // bit2k->pos14, bit2k+1->pos30 (fp16 2.0)
        m.u = (t << (14 - 2 * k)) & 0x40004000u;
        af.p[k] = mx * m.v;
      }
      acc[gi][0] = __builtin_amdgcn_mfma_f32_16x16x32_f16(af.v, b0, acc[gi][0], 0, 0, 0);
      acc[gi][1] = __builtin_amdgcn_mfma_f32_16x16x32_f16(af.v, b1, acc[gi][1], 0, 0, 0);
      acc[gi][2] = __builtin_amdgcn_mfma_f32_16x16x32_f16(af.v, b2, acc[gi][2], 0, 0, 0);
      acc[gi][3] = __builtin_amdgcn_mfma_f32_16x16x32_f16(af.v, b3, acc[gi][3], 0, 0, 0);
      acc[gi][4] = __builtin_amdgcn_mfma_f32_16x16x32_f16(af.v, ones.v, acc[gi][4], 0, 0, 0);
    }
  };

  stage(seg0, 0);
  __syncthreads();
#pragma unroll 1
  for (int p2 = 0; p2 < 16; ++p2) {
    stage(seg1, 2 * p2 + 1);
    compute(seg0);
    __syncthreads();
    if (p2 < 15) stage(seg0, 2 * p2 + 2);
    compute(seg1);
    __syncthreads();
  }

  // ---- chunked cross-jseg reduction, fully unrolled (static acc indices) ----
  float* red = (float*)lds;               // 3 segs x 4 gi x 64 lanes x 16B = 12288 B
#pragma unroll
  for (int cc = 0; cc < 5; ++cc) {
    if (jseg != 0) {
#pragma unroll
      for (int gi = 0; gi < 4; ++gi)
        *(f32x4*)(red + (((jseg - 1) * 4 + gi) * 64 + lane) * 4) = acc[gi][cc];
    }
    __syncthreads();
    if (jseg == 0) {
#pragma unroll
      for (int s = 0; s < 3; ++s)
#pragma unroll
        for (int gi = 0; gi < 4; ++gi)
          acc[gi][cc] += *(const f32x4*)(red + ((s * 4 + gi) * 64 + lane) * 4);
    }
    __syncthreads();
  }

  if (jseg == 0) {
#pragma unroll
    for (int gi = 0; gi < 4; ++gi) {
#pragma unroll
      for (int reg = 0; reg < 4; ++reg) {
        float inv = 1.0f / acc[gi][4][reg];
        int row = r0 + gi * 16 + grp * 4 + reg;
        float* op = out + (size_t)row * (NH * FO) + h * FO + row16;
        op[0]  = acc[gi][0][reg] * inv;
        op[16] = acc[gi][1][reg] * inv;
        op[32] = acc[gi][2][reg] * inv;
        op[48] = acc[gi][3][reg] * inv;
      }
    }
  }
}

extern "C" void kernel_launch(void* const* d_in, const int* in_sizes, int n_in,
                              void* d_out, int out_size, void* d_ws, size_t ws_size,
                              hipStream_t stream) {
  const float* X  = (const float*)d_in[0];
  const int* adj  = (const int*)d_in[1];
  const float* W  = (const float*)d_in[2];
  const float* a  = (const float*)d_in[3];
  float* out = (float*)d_out;
  char* ws = (char*)d_ws;

  unsigned short* WbT    = (unsigned short*)(ws + 0);          // 512 KB
  unsigned* adjbitsT     = (unsigned*)(ws + 524288);           // 2 MB
  unsigned short* Whfrag = (unsigned short*)(ws + 2621440);    // 4 MB
  unsigned short* WAh    = (unsigned short*)(ws + 6815744);    // 16 KB
  float* Rf              = (float*)(ws + 6832128);             // 128 KB
  unsigned short* E1h    = (unsigned short*)(ws + 6963200);    // 64 KB
  unsigned short* E2h    = (unsigned short*)(ws + 7028736);    // 64 KB (total ~6.8 MB)

  prep_kernel<<<3104, 256, 0, stream>>>(adj, W, a, WbT, adjbitsT, WAh);
  proj_sd_kernel<<<544, 512, 0, stream>>>(X, WbT, WAh, Whfrag, Rf, E1h, E2h);
  gat_kernel<<<dim3(64, 8), 256, 0, stream>>>(adjbitsT, Whfrag, Rf, E1h, E2h, out);
}

// Round 16
// 77.898 us; speedup vs baseline: 1.1185x; 1.0906x over previous
//
#include <hip/hip_runtime.h>
#include <stdint.h>

// GAT: N=4096, F_in=512, H=8, F_out=64.
// P_ij = A_i·max(E1_j, R_i·E2_j)·adj, R_i = e^{-0.8 s_i}; A_i cancels in softmax.
// Round 16: gat main loop is REGISTER-direct (no LDS, no barriers, no
// global_load_lds vmcnt-drain): B/E/adj tiles -> VGPRs from L2-resident tables,
// manual tA/tB rotation with memory-clobber fence to pin prefetch. Quad-af
// (64 rows/wave), 4 jseg waves/block, in-block LDS reduce only at the end.
// prep/proj restored to the r11 (79.8us) versions.

#define NN 4096
#define FIN 512
#define NH 8
#define FO 64

typedef _Float16 f16x8 __attribute__((ext_vector_type(8)));
typedef _Float16 f16x2 __attribute__((ext_vector_type(2)));
typedef __attribute__((ext_vector_type(4))) float f32x4;

union H8 { f16x8 v; f16x2 p[4]; unsigned u[4]; };
union U2 { unsigned u; f16x2 v; };

__device__ __forceinline__ unsigned short f2h(float f) {
  _Float16 h = (_Float16)f;               // RNE
  return __builtin_bit_cast(unsigned short, h);
}

// ---------------- prep: adj->bitsT, X->fp16, W->WbT(fp16), wa = W^T a (r11) -------
__global__ __launch_bounds__(256) void prep_kernel(
    const float* __restrict__ X, const int* __restrict__ adj, const float* __restrict__ W,
    const float* __restrict__ a,
    unsigned short* __restrict__ Xh, unsigned short* __restrict__ WbT,
    unsigned* __restrict__ adjbitsT, unsigned short* __restrict__ WAh) {
  int bid = blockIdx.x, tid = threadIdx.x;
  if (bid < 2048) {                       // adj -> bit words, transposed [jt][r]
    int item = bid * 256 + tid;           // item = jt*4096 + r
    int jt = item >> 12, r = item & 4095;
    const int* p = adj + (size_t)r * NN + jt * 32;
    unsigned bits = 0;
#pragma unroll
    for (int b = 0; b < 32; b += 4) {
      int4 v = *(const int4*)(p + b);
      bits |= (unsigned)(v.x & 1) << b;
      bits |= (unsigned)(v.y & 1) << (b + 1);
      bits |= (unsigned)(v.z & 1) << (b + 2);
      bits |= (unsigned)(v.w & 1) << (b + 3);
    }
    adjbitsT[item] = bits;
  } else if (bid < 4096) {                // X -> fp16
    int item = (bid - 2048) * 256 + tid;
    float4 v = ((const float4*)X)[item];
    ushort4 o;
    o.x = f2h(v.x); o.y = f2h(v.y); o.z = f2h(v.z); o.w = f2h(v.w);
    ((ushort4*)Xh)[item] = o;
  } else if (bid < 5120) {                // W[h][k][o] -> WbT[h][o][k], coalesced READ
    int item = (bid - 4096) * 256 + tid;  // item = (h,k,o): wave reads 256B segment
    int o = item & 63, k = (item >> 6) & 511, h = item >> 15;
    WbT[h * 32768 + o * 512 + k] = f2h(W[h * 32768 + k * 64 + o]);
  } else {                                // wa[t][k] = sum_o W[h][k][o] * a[h][which*64+o]
    int item = (bid - 5120) * 256 + tid;  // 8192 items: t = h*2+which, k
    int h = item >> 10, which = (item >> 9) & 1, k = item & 511;
    const float4* wp = (const float4*)(W + ((size_t)h * FIN + k) * FO);
    const float4* ap = (const float4*)(a + h * 128 + which * 64);
    float s = 0.f;
#pragma unroll
    for (int o4 = 0; o4 < 16; ++o4) {
      float4 w4 = wp[o4], a4 = ap[o4];
      s += w4.x * a4.x + w4.y * a4.y + w4.z * a4.z + w4.w * a4.w;
    }
    WAh[(h * 2 + which) * FIN + k] = f2h(s);
  }
}

// ---------------- proj (+sd): r11 version (reads Xh fp16) -------------------------
// D layout (16x16x32): col = lane&15, row = (lane>>4)*4 + reg   [m89]
__global__ __launch_bounds__(512, 4) void proj_sd_kernel(
    const unsigned short* __restrict__ Xh, const unsigned short* __restrict__ WbT,
    const unsigned short* __restrict__ WAh,
    unsigned short* __restrict__ Whfrag, float* __restrict__ Rf,
    unsigned short* __restrict__ E1h, unsigned short* __restrict__ E2h) {
  __shared__ float red[4 * 64 * 20];      // 20KB partial store
  int lane = threadIdx.x & 63, wave = threadIdx.x >> 6;
  int row16 = lane & 15, grp = lane >> 4;
  int bx = blockIdx.x;
  if (bx >= 512) {                        // sd: [s,d]x8 = X @ WA  (16 cols, K=512)
    int i0 = ((bx - 512) * 8 + wave) * 16;
    if (i0 >= NN) return;
    f32x4 acc = {0, 0, 0, 0};
    const unsigned short* xb = Xh + (size_t)(i0 + row16) * FIN + grp * 8;
    const unsigned short* wb = WAh + row16 * FIN + grp * 8;
#pragma unroll
    for (int k0 = 0; k0 < FIN; k0 += 32)
      acc = __builtin_amdgcn_mfma_f32_16x16x32_f16(*(const f16x8*)(xb + k0),
                                                   *(const f16x8*)(wb + k0), acc, 0, 0, 0);
    int hh = row16 >> 1;
#pragma unroll
    for (int reg = 0; reg < 4; ++reg) {
      int rr = i0 + grp * 4 + reg;
      float v = acc[reg];
      if (row16 & 1) {                    // d -> col tables fp16, PRE-HALVED
        E1h[hh * NN + rr] = f2h(0.5f * __expf(v));
        E2h[hh * NN + rr] = f2h(0.5f * __expf(0.2f * v));
      } else {                            // s -> row table R = e^{-0.8 s}
        Rf[hh * NN + rr] = __expf(-0.8f * v);
      }
    }
    return;
  }
  int kh = wave >> 2, jb = wave & 3;
  int job = bx * 4 + jb;                  // 2048 jobs = 256 rowtiles x 8 heads
  int h = job & 7, rt = job >> 3;
  int i0 = rt * 16;
  f32x4 acc[4] = {{0,0,0,0},{0,0,0,0},{0,0,0,0},{0,0,0,0}};
  const unsigned short* xb = Xh + (size_t)(i0 + row16) * FIN + kh * 256 + grp * 8;
  const unsigned short* wb = WbT + h * (FO * FIN) + row16 * FIN + kh * 256 + grp * 8;
#pragma unroll
  for (int k0 = 0; k0 < 256; k0 += 32) {
    f16x8 af = *(const f16x8*)(xb + k0);
#pragma unroll
    for (int cb = 0; cb < 4; ++cb)
      acc[cb] = __builtin_amdgcn_mfma_f32_16x16x32_f16(
          af, *(const f16x8*)(wb + cb * 16 * FIN + k0), acc[cb], 0, 0, 0);
  }
  if (kh == 1) {
    float* q = red + (jb * 64 + lane) * 20;
#pragma unroll
    for (int cb = 0; cb < 4; ++cb) *(f32x4*)(q + cb * 4) = acc[cb];
  }
  __syncthreads();
  if (kh == 0) {
    const float* q = red + (jb * 64 + lane) * 20;
#pragma unroll
    for (int cb = 0; cb < 4; ++cb) acc[cb] += *(const f32x4*)(q + cb * 4);
    // Whfrag[h][jt][cb][l][e] = Wh[jt*32 + (l>>4)*8 + e][cb*16 + (l&15)]
    int jt = i0 >> 5;
    int kk0 = (i0 & 31) + grp * 4;
    int tl = (kk0 >> 3) * 16 + row16;
    int e0 = kk0 & 7;
#pragma unroll
    for (int cb = 0; cb < 4; ++cb) {
      ushort4 pk;
      pk.x = f2h(acc[cb][0]); pk.y = f2h(acc[cb][1]);
      pk.z = f2h(acc[cb][2]); pk.w = f2h(acc[cb][3]);
      *(ushort4*)(Whfrag + (((size_t)h * 128 + jt) * 4 + cb) * 512 + tl * 8 + e0) = pk;
    }
  }
}

// ---------------- gat: register-direct quad-af, no LDS in main loop ---------------
struct Tile {
  f16x8 b0, b1, b2, b3;    // B-fragments (16 VGPR)
  f16x8 e1, e2;            // E tables    (8 VGPR)
  unsigned aw0, aw1, aw2, aw3;  // adj words per gi (4 VGPR)
};

__global__ __launch_bounds__(256, 2) void gat_kernel(
    const unsigned* __restrict__ adjbitsT, const unsigned short* __restrict__ Whfrag,
    const float* __restrict__ Rf, const unsigned short* __restrict__ E1h,
    const unsigned short* __restrict__ E2h, float* __restrict__ out) {
  __shared__ __align__(16) float red[3072];   // 12 KB reduce overlay
  int h = blockIdx.y;
  int lane = threadIdx.x & 63, jseg = threadIdx.x >> 6;
  int row16 = lane & 15, grp = lane >> 4;
  int r0 = blockIdx.x * 64;
  int jt0 = jseg * 32;

  f16x2 Rh[4];
#pragma unroll
  for (int gi = 0; gi < 4; ++gi) {
    _Float16 rv = (_Float16)Rf[h * NN + r0 + gi * 16 + row16];
    Rh[gi][0] = rv; Rh[gi][1] = rv;
  }

  H8 ones;
#pragma unroll
  for (int k = 0; k < 4; ++k) ones.u[k] = 0x3C003C00u;   // fp16 1.0 pairs

  const unsigned short* wsrc = Whfrag + (size_t)h * 262144 + (size_t)jt0 * 2048 + lane * 8;
  const unsigned short* e1p = E1h + h * NN + jt0 * 32 + grp * 8;
  const unsigned short* e2p = E2h + h * NN + jt0 * 32 + grp * 8;
  const unsigned* ap = adjbitsT + (size_t)jt0 * NN + r0 + row16;

  f32x4 acc[4][5];
#pragma unroll
  for (int gi = 0; gi < 4; ++gi)
#pragma unroll
    for (int cc = 0; cc < 5; ++cc) acc[gi][cc] = (f32x4){0, 0, 0, 0};

  auto ld = [&](int p, Tile& t) {          // 10 L2-hot loads -> VGPRs
    const unsigned short* bs = wsrc + (size_t)p * 2048;
    t.b0 = *(const f16x8*)(bs);
    t.b1 = *(const f16x8*)(bs + 512);
    t.b2 = *(const f16x8*)(bs + 1024);
    t.b3 = *(const f16x8*)(bs + 1536);
    t.e1 = *(const f16x8*)(e1p + p * 32);
    t.e2 = *(const f16x8*)(e2p + p * 32);
    const unsigned* aq = ap + (size_t)p * NN;
    t.aw0 = aq[0]; t.aw1 = aq[16]; t.aw2 = aq[32]; t.aw3 = aq[48];
  };

  auto compute = [&](const Tile& t) {
    H8 e1, e2;
    e1.v = t.e1; e2.v = t.e2;
    unsigned aw[4] = {t.aw0, t.aw1, t.aw2, t.aw3};
#pragma unroll
    for (int gi = 0; gi < 4; ++gi) {
      unsigned bb = (aw[gi] >> (grp * 8)) & 0xffu;
      unsigned tt = bb | (bb << 15);       // bit k at {k, k+15}
      H8 af;
#pragma unroll
      for (int k = 0; k < 4; ++k) {
        f16x2 mx = __builtin_elementwise_max(e1.p[k], Rh[gi] * e2.p[k]);
        U2 m;                              // bit2k->pos14, bit2k+1->pos30 (fp16 2.0)
        m.u = (tt << (14 - 2 * k)) & 0x40004000u;
        af.p[k] = mx * m.v;
      }
      acc[gi][0] = __builtin_amdgcn_mfma_f32_16x16x32_f16(af.v, t.b0, acc[gi][0], 0, 0, 0);
      acc[gi][1] = __builtin_amdgcn_mfma_f32_16x16x32_f16(af.v, t.b1, acc[gi][1], 0, 0, 0);
      acc[gi][2] = __builtin_amdgcn_mfma_f32_16x16x32_f16(af.v, t.b2, acc[gi][2], 0, 0, 0);
      acc[gi][3] = __builtin_amdgcn_mfma_f32_16x16x32_f16(af.v, t.b3, acc[gi][3], 0, 0, 0);
      acc[gi][4] = __builtin_amdgcn_mfma_f32_16x16x32_f16(af.v, ones.v, acc[gi][4], 0, 0, 0);
    }
  };

  // ---- barrier-free register pipeline: loads pinned above compute by mem-fence ----
  Tile tA, tB;
  ld(0, tA);
#pragma unroll 1
  for (int p2 = 0; p2 < 15; ++p2) {
    ld(2 * p2 + 1, tB);
    asm volatile("" ::: "memory");         // loads cannot sink below this point
    compute(tA);
    ld(2 * p2 + 2, tA);
    asm volatile("" ::: "memory");
    compute(tB);
  }
  ld(31, tB);
  compute(tA);
  compute(tB);

  // ---- chunked cross-jseg reduction (12 KB overlay, static indices) ----
  __syncthreads();
#pragma unroll
  for (int cc = 0; cc < 5; ++cc) {
    if (jseg != 0) {
#pragma unroll
      for (int gi = 0; gi < 4; ++gi)
        *(f32x4*)(red + (((jseg - 1) * 4 + gi) * 64 + lane) * 4) = acc[gi][cc];
    }
    __syncthreads();
    if (jseg == 0) {
#pragma unroll
      for (int s = 0; s < 3; ++s)
#pragma unroll
        for (int gi = 0; gi < 4; ++gi)
          acc[gi][cc] += *(const f32x4*)(red + ((s * 4 + gi) * 64 + lane) * 4);
    }
    __syncthreads();
  }

  if (jseg == 0) {
#pragma unroll
    for (int gi = 0; gi < 4; ++gi) {
#pragma unroll
      for (int reg = 0; reg < 4; ++reg) {
        float inv = 1.0f / acc[gi][4][reg];
        int row = r0 + gi * 16 + grp * 4 + reg;
        float* op = out + (size_t)row * (NH * FO) + h * FO + row16;
        op[0]  = acc[gi][0][reg] * inv;
        op[16] = acc[gi][1][reg] * inv;
        op[32] = acc[gi][2][reg] * inv;
        op[48] = acc[gi][3][reg] * inv;
      }
    }
  }
}

extern "C" void kernel_launch(void* const* d_in, const int* in_sizes, int n_in,
                              void* d_out, int out_size, void* d_ws, size_t ws_size,
                              hipStream_t stream) {
  const float* X  = (const float*)d_in[0];
  const int* adj  = (const int*)d_in[1];
  const float* W  = (const float*)d_in[2];
  const float* a  = (const float*)d_in[3];
  float* out = (float*)d_out;
  char* ws = (char*)d_ws;

  unsigned short* Xh     = (unsigned short*)(ws + 0);          // 4 MB
  unsigned short* WbT    = (unsigned short*)(ws + 4194304);    // 512 KB
  unsigned* adjbitsT     = (unsigned*)(ws + 4718592);          // 2 MB
  unsigned short* Whfrag = (unsigned short*)(ws + 6815744);    // 4 MB
  unsigned short* WAh    = (unsigned short*)(ws + 11010048);   // 16 KB
  float* Rf              = (float*)(ws + 11026432);            // 128 KB
  unsigned short* E1h    = (unsigned short*)(ws + 11288576);   // 64 KB
  unsigned short* E2h    = (unsigned short*)(ws + 11354112);   // 64 KB (total ~11.4 MB)

  prep_kernel<<<5152, 256, 0, stream>>>(X, adj, W, a, Xh, WbT, adjbitsT, WAh);
  proj_sd_kernel<<<544, 512, 0, stream>>>(Xh, WbT, WAh, Whfrag, Rf, E1h, E2h);
  gat_kernel<<<dim3(64, 8), 256, 0, stream>>>(adjbitsT, Whfrag, Rf, E1h, E2h, out);
}

// Round 17
// 77.202 us; speedup vs baseline: 1.1286x; 1.0090x over previous
//
#include <hip/hip_runtime.h>
#include <stdint.h>

// GAT: N=4096, F_in=512, H=8, F_out=64.
// P_ij = A_i·max(E1_j, R_i·E2_j)·adj, R_i = e^{-0.8 s_i}; A_i cancels in softmax.
// Round 17: overlap the HBM-bound adj-pack with the latency-bound proj by fusing
// them into ONE dispatch (proj blocks bx<544, adj-pack blocks bx>=544). proj reads
// f32 X directly (ld_cvt8) so prep shrinks to W-transpose + WA (~2us). gat is the
// r16 register-direct quad-af, unchanged.

#define NN 4096
#define FIN 512
#define NH 8
#define FO 64

typedef _Float16 f16x8 __attribute__((ext_vector_type(8)));
typedef _Float16 f16x2 __attribute__((ext_vector_type(2)));
typedef __attribute__((ext_vector_type(4))) float f32x4;

union H8 { f16x8 v; f16x2 p[4]; unsigned u[4]; };
union U2 { unsigned u; f16x2 v; };

__device__ __forceinline__ unsigned short f2h(float f) {
  _Float16 h = (_Float16)f;               // RNE
  return __builtin_bit_cast(unsigned short, h);
}

__device__ __forceinline__ f16x8 ld_cvt8(const float* p) {   // f32x8 -> f16x8
  float4 a = *(const float4*)p, b = *(const float4*)(p + 4);
  f16x8 r;
  r[0] = (_Float16)a.x; r[1] = (_Float16)a.y; r[2] = (_Float16)a.z; r[3] = (_Float16)a.w;
  r[4] = (_Float16)b.x; r[5] = (_Float16)b.y; r[6] = (_Float16)b.z; r[7] = (_Float16)b.w;
  return r;
}

// ---------------- prep_w: W->WbT(fp16) coalesced-read + wa = W^T a (tiny) ---------
__global__ __launch_bounds__(256) void prep_w_kernel(
    const float* __restrict__ W, const float* __restrict__ a,
    unsigned short* __restrict__ WbT, unsigned short* __restrict__ WAh) {
  int bid = blockIdx.x, tid = threadIdx.x;
  if (bid < 1024) {                       // W[h][k][o] -> WbT[h][o][k], coalesced READ
    int item = bid * 256 + tid;           // 262144 items = (h,k,o)
    int o = item & 63, k = (item >> 6) & 511, h = item >> 15;
    WbT[h * 32768 + o * 512 + k] = f2h(W[h * 32768 + k * 64 + o]);
  } else {                                // wa[t][k] = sum_o W[h][k][o] * a[h][which*64+o]
    int item = (bid - 1024) * 256 + tid;  // 8192 items: t = h*2+which, k
    int h = item >> 10, which = (item >> 9) & 1, k = item & 511;
    const float4* wp = (const float4*)(W + ((size_t)h * FIN + k) * FO);
    const float4* ap = (const float4*)(a + h * 128 + which * 64);
    float s = 0.f;
#pragma unroll
    for (int o4 = 0; o4 < 16; ++o4) {
      float4 w4 = wp[o4], a4 = ap[o4];
      s += w4.x * a4.x + w4.y * a4.y + w4.z * a4.z + w4.w * a4.w;
    }
    WAh[(h * 2 + which) * FIN + k] = f2h(s);
  }
}

// ---------------- fused: proj (+sd) blocks bx<544  |  adj-pack blocks bx>=544 ------
// D layout (16x16x32): col = lane&15, row = (lane>>4)*4 + reg   [m89]
__global__ __launch_bounds__(512, 4) void proj_adj_kernel(
    const float* __restrict__ X, const int* __restrict__ adj,
    const unsigned short* __restrict__ WbT, const unsigned short* __restrict__ WAh,
    unsigned short* __restrict__ Whfrag, float* __restrict__ Rf,
    unsigned short* __restrict__ E1h, unsigned short* __restrict__ E2h,
    unsigned* __restrict__ adjbitsT) {
  __shared__ float red[4 * 64 * 20];      // 20KB partial store (proj blocks only)
  int lane = threadIdx.x & 63, wave = threadIdx.x >> 6;
  int row16 = lane & 15, grp = lane >> 4;
  int bx = blockIdx.x;
  if (bx >= 544) {                        // ---- adj-pack: HBM stream, overlaps proj
    int item = (bx - 544) * 512 + threadIdx.x;   // item = jt*4096 + r
    int jt = item >> 12, r = item & 4095;
    const int* p = adj + (size_t)r * NN + jt * 32;
    unsigned bits = 0;
#pragma unroll
    for (int b = 0; b < 32; b += 4) {
      int4 v = *(const int4*)(p + b);
      bits |= (unsigned)(v.x & 1) << b;
      bits |= (unsigned)(v.y & 1) << (b + 1);
      bits |= (unsigned)(v.z & 1) << (b + 2);
      bits |= (unsigned)(v.w & 1) << (b + 3);
    }
    adjbitsT[item] = bits;
    return;
  }
  if (bx >= 512) {                        // sd: [s,d]x8 = X @ WA  (16 cols, K=512)
    int i0 = ((bx - 512) * 8 + wave) * 16;
    if (i0 >= NN) return;
    f32x4 acc = {0, 0, 0, 0};
    const float* xb = X + (size_t)(i0 + row16) * FIN + grp * 8;
    const unsigned short* wb = WAh + row16 * FIN + grp * 8;
#pragma unroll
    for (int k0 = 0; k0 < FIN; k0 += 32)
      acc = __builtin_amdgcn_mfma_f32_16x16x32_f16(ld_cvt8(xb + k0),
                                                   *(const f16x8*)(wb + k0), acc, 0, 0, 0);
    int hh = row16 >> 1;
#pragma unroll
    for (int reg = 0; reg < 4; ++reg) {
      int rr = i0 + grp * 4 + reg;
      float v = acc[reg];
      if (row16 & 1) {                    // d -> col tables fp16, PRE-HALVED
        E1h[hh * NN + rr] = f2h(0.5f * __expf(v));
        E2h[hh * NN + rr] = f2h(0.5f * __expf(0.2f * v));
      } else {                            // s -> row table R = e^{-0.8 s}
        Rf[hh * NN + rr] = __expf(-0.8f * v);
      }
    }
    return;
  }
  int kh = wave >> 2, jb = wave & 3;
  int job = bx * 4 + jb;                  // 2048 jobs = 256 rowtiles x 8 heads
  int h = job & 7, rt = job >> 3;
  int i0 = rt * 16;
  f32x4 acc[4] = {{0,0,0,0},{0,0,0,0},{0,0,0,0},{0,0,0,0}};
  const float* xb = X + (size_t)(i0 + row16) * FIN + kh * 256 + grp * 8;
  const unsigned short* wb = WbT + h * (FO * FIN) + row16 * FIN + kh * 256 + grp * 8;
#pragma unroll
  for (int k0 = 0; k0 < 256; k0 += 32) {
    f16x8 af = ld_cvt8(xb + k0);
#pragma unroll
    for (int cb = 0; cb < 4; ++cb)
      acc[cb] = __builtin_amdgcn_mfma_f32_16x16x32_f16(
          af, *(const f16x8*)(wb + cb * 16 * FIN + k0), acc[cb], 0, 0, 0);
  }
  if (kh == 1) {
    float* q = red + (jb * 64 + lane) * 20;
#pragma unroll
    for (int cb = 0; cb < 4; ++cb) *(f32x4*)(q + cb * 4) = acc[cb];
  }
  __syncthreads();
  if (kh == 0) {
    const float* q = red + (jb * 64 + lane) * 20;
#pragma unroll
    for (int cb = 0; cb < 4; ++cb) acc[cb] += *(const f32x4*)(q + cb * 4);
    // Whfrag[h][jt][cb][l][e] = Wh[jt*32 + (l>>4)*8 + e][cb*16 + (l&15)]
    int jt = i0 >> 5;
    int kk0 = (i0 & 31) + grp * 4;
    int tl = (kk0 >> 3) * 16 + row16;
    int e0 = kk0 & 7;
#pragma unroll
    for (int cb = 0; cb < 4; ++cb) {
      ushort4 pk;
      pk.x = f2h(acc[cb][0]); pk.y = f2h(acc[cb][1]);
      pk.z = f2h(acc[cb][2]); pk.w = f2h(acc[cb][3]);
      *(ushort4*)(Whfrag + (((size_t)h * 128 + jt) * 4 + cb) * 512 + tl * 8 + e0) = pk;
    }
  }
}

// ---------------- gat: register-direct quad-af (r16, unchanged) -------------------
struct Tile {
  f16x8 b0, b1, b2, b3;    // B-fragments (16 VGPR)
  f16x8 e1, e2;            // E tables    (8 VGPR)
  unsigned aw0, aw1, aw2, aw3;  // adj words per gi (4 VGPR)
};

__global__ __launch_bounds__(256, 2) void gat_kernel(
    const unsigned* __restrict__ adjbitsT, const unsigned short* __restrict__ Whfrag,
    const float* __restrict__ Rf, const unsigned short* __restrict__ E1h,
    const unsigned short* __restrict__ E2h, float* __restrict__ out) {
  __shared__ __align__(16) float red[3072];   // 12 KB reduce overlay
  int h = blockIdx.y;
  int lane = threadIdx.x & 63, jseg = threadIdx.x >> 6;
  int row16 = lane & 15, grp = lane >> 4;
  int r0 = blockIdx.x * 64;
  int jt0 = jseg * 32;

  f16x2 Rh[4];
#pragma unroll
  for (int gi = 0; gi < 4; ++gi) {
    _Float16 rv = (_Float16)Rf[h * NN + r0 + gi * 16 + row16];
    Rh[gi][0] = rv; Rh[gi][1] = rv;
  }

  H8 ones;
#pragma unroll
  for (int k = 0; k < 4; ++k) ones.u[k] = 0x3C003C00u;   // fp16 1.0 pairs

  const unsigned short* wsrc = Whfrag + (size_t)h * 262144 + (size_t)jt0 * 2048 + lane * 8;
  const unsigned short* e1p = E1h + h * NN + jt0 * 32 + grp * 8;
  const unsigned short* e2p = E2h + h * NN + jt0 * 32 + grp * 8;
  const unsigned* ap = adjbitsT + (size_t)jt0 * NN + r0 + row16;

  f32x4 acc[4][5];
#pragma unroll
  for (int gi = 0; gi < 4; ++gi)
#pragma unroll
    for (int cc = 0; cc < 5; ++cc) acc[gi][cc] = (f32x4){0, 0, 0, 0};

  auto ld = [&](int p, Tile& t) {          // 10 L2-hot loads -> VGPRs
    const unsigned short* bs = wsrc + (size_t)p * 2048;
    t.b0 = *(const f16x8*)(bs);
    t.b1 = *(const f16x8*)(bs + 512);
    t.b2 = *(const f16x8*)(bs + 1024);
    t.b3 = *(const f16x8*)(bs + 1536);
    t.e1 = *(const f16x8*)(e1p + p * 32);
    t.e2 = *(const f16x8*)(e2p + p * 32);
    const unsigned* aq = ap + (size_t)p * NN;
    t.aw0 = aq[0]; t.aw1 = aq[16]; t.aw2 = aq[32]; t.aw3 = aq[48];
  };

  auto compute = [&](const Tile& t) {
    H8 e1, e2;
    e1.v = t.e1; e2.v = t.e2;
    unsigned aw[4] = {t.aw0, t.aw1, t.aw2, t.aw3};
#pragma unroll
    for (int gi = 0; gi < 4; ++gi) {
      unsigned bb = (aw[gi] >> (grp * 8)) & 0xffu;
      unsigned tt = bb | (bb << 15);       // bit k at {k, k+15}
      H8 af;
#pragma unroll
      for (int k = 0; k < 4; ++k) {
        f16x2 mx = __builtin_elementwise_max(e1.p[k], Rh[gi] * e2.p[k]);
        U2 m;                              // bit2k->pos14, bit2k+1->pos30 (fp16 2.0)
        m.u = (tt << (14 - 2 * k)) & 0x40004000u;
        af.p[k] = mx * m.v;
      }
      acc[gi][0] = __builtin_amdgcn_mfma_f32_16x16x32_f16(af.v, t.b0, acc[gi][0], 0, 0, 0);
      acc[gi][1] = __builtin_amdgcn_mfma_f32_16x16x32_f16(af.v, t.b1, acc[gi][1], 0, 0, 0);
      acc[gi][2] = __builtin_amdgcn_mfma_f32_16x16x32_f16(af.v, t.b2, acc[gi][2], 0, 0, 0);
      acc[gi][3] = __builtin_amdgcn_mfma_f32_16x16x32_f16(af.v, t.b3, acc[gi][3], 0, 0, 0);
      acc[gi][4] = __builtin_amdgcn_mfma_f32_16x16x32_f16(af.v, ones.v, acc[gi][4], 0, 0, 0);
    }
  };

  // ---- barrier-free register pipeline: loads pinned above compute by mem-fence ----
  Tile tA, tB;
  ld(0, tA);
#pragma unroll 1
  for (int p2 = 0; p2 < 15; ++p2) {
    ld(2 * p2 + 1, tB);
    asm volatile("" ::: "memory");         // loads cannot sink below this point
    compute(tA);
    ld(2 * p2 + 2, tA);
    asm volatile("" ::: "memory");
    compute(tB);
  }
  ld(31, tB);
  compute(tA);
  compute(tB);

  // ---- chunked cross-jseg reduction (12 KB overlay, static indices) ----
  __syncthreads();
#pragma unroll
  for (int cc = 0; cc < 5; ++cc) {
    if (jseg != 0) {
#pragma unroll
      for (int gi = 0; gi < 4; ++gi)
        *(f32x4*)(red + (((jseg - 1) * 4 + gi) * 64 + lane) * 4) = acc[gi][cc];
    }
    __syncthreads();
    if (jseg == 0) {
#pragma unroll
      for (int s = 0; s < 3; ++s)
#pragma unroll
        for (int gi = 0; gi < 4; ++gi)
          acc[gi][cc] += *(const f32x4*)(red + ((s * 4 + gi) * 64 + lane) * 4);
    }
    __syncthreads();
  }

  if (jseg == 0) {
#pragma unroll
    for (int gi = 0; gi < 4; ++gi) {
#pragma unroll
      for (int reg = 0; reg < 4; ++reg) {
        float inv = 1.0f / acc[gi][4][reg];
        int row = r0 + gi * 16 + grp * 4 + reg;
        float* op = out + (size_t)row * (NH * FO) + h * FO + row16;
        op[0]  = acc[gi][0][reg] * inv;
        op[16] = acc[gi][1][reg] * inv;
        op[32] = acc[gi][2][reg] * inv;
        op[48] = acc[gi][3][reg] * inv;
      }
    }
  }
}

extern "C" void kernel_launch(void* const* d_in, const int* in_sizes, int n_in,
                              void* d_out, int out_size, void* d_ws, size_t ws_size,
                              hipStream_t stream) {
  const float* X  = (const float*)d_in[0];
  const int* adj  = (const int*)d_in[1];
  const float* W  = (const float*)d_in[2];
  const float* a  = (const float*)d_in[3];
  float* out = (float*)d_out;
  char* ws = (char*)d_ws;

  unsigned short* WbT    = (unsigned short*)(ws + 0);          // 512 KB
  unsigned* adjbitsT     = (unsigned*)(ws + 524288);           // 2 MB
  unsigned short* Whfrag = (unsigned short*)(ws + 2621440);    // 4 MB
  unsigned short* WAh    = (unsigned short*)(ws + 6815744);    // 16 KB
  float* Rf              = (float*)(ws + 6832128);             // 128 KB
  unsigned short* E1h    = (unsigned short*)(ws + 6963200);    // 64 KB
  unsigned short* E2h    = (unsigned short*)(ws + 7028736);    // 64 KB (total ~6.8 MB)

  prep_w_kernel<<<1056, 256, 0, stream>>>(W, a, WbT, WAh);
  proj_adj_kernel<<<1568, 512, 0, stream>>>(X, adj, WbT, WAh, Whfrag, Rf, E1h, E2h,
                                            adjbitsT);
  gat_kernel<<<dim3(64, 8), 256, 0, stream>>>(adjbitsT, Whfrag, Rf, E1h, E2h, out);
}